// Round 4
// baseline (374.761 us; speedup 1.0000x reference)
//
#include <hip/hip_runtime.h>
#include <hip/hip_bf16.h>
#include <math.h>

#define BB   16
#define SS   2048
#define HH   768
#define MAXN 400
#define LBL  97
#define MIDD 768
#define KTOT 1536   // 2*HH

// ---------------------------------------------------------------------------
// K1: fused gather + GEMM1 + bias + relu:  h[b,i,:] = relu(marker(b,i) @ W1 + b1)
// marker(b,i) = concat(outs[b,pos1,:], outs[b,pos2,:]), pos = clip(start+4i(+2))
// tile: BM=32 rows x BN=128 cols x BK=32, 256 thr, micro 4x4 (16 acc)
// BK=32: 1024 compute-cycles per barrier pair; prefetch covers HBM latency.
// As padded 32->36 words/row: A-transpose scalar writes 8-way -> 4-way banks.
// ---------------------------------------------------------------------------
__global__ __launch_bounds__(256, 4)
void k1_gemm1(const float* __restrict__ outs, const int* __restrict__ rels_pos,
              const float* __restrict__ W1, const float* __restrict__ b1,
              float* __restrict__ h)
{
    const int b  = blockIdx.z;
    const int n0 = blockIdx.x * 128;
    const int i0 = blockIdx.y * 32;
    const int num = rels_pos[2 * b + 1];
    if (i0 >= num) return;                       // whole tile masked
    const int start = rels_pos[2 * b + 0];

    __shared__ __align__(16) float As[32][36];   // [k][m] transposed, padded (4-way banks)
    __shared__ __align__(16) float Bs[32][128];  // [k][n], 16 KB

    const int tid = threadIdx.x;

    // --- staging maps ---
    // A: each thread loads one float4 of a gathered row: row m_st, k-chunk kq
    const int m_st = tid >> 3;                   // 0..31
    const int kq   = (tid & 7) << 2;             // 0,4,...,28
    const int irow = i0 + m_st;                  // may exceed num: clamped reads, safe
    int p1 = start + 4 * irow;     p1 = min(max(p1, 0), SS - 1);
    int p2 = start + 4 * irow + 2; p2 = min(max(p2, 0), SS - 1);
    const float* arow1 = outs + (size_t)(b * SS + p1) * HH;
    const float* arow2 = outs + (size_t)(b * SS + p2) * HH;
    // B: each thread loads 4 float4 of W1 tile: rows kb,kb+16 x cols ng*4, ng*4+64
    const int kb = tid >> 4;                     // 0..15
    const int ng = tid & 15;                     // 0..15

    // --- micro-tile: rows rg*4..+3, cols cg*4..+3 ---
    const int cg = tid & 31;                     // 0..31
    const int rg = tid >> 5;                     // 0..7

    float acc[4][4];
    #pragma unroll
    for (int r = 0; r < 4; ++r)
        #pragma unroll
        for (int c = 0; c < 4; ++c) acc[r][c] = 0.f;

    // register prefetch (hide global latency under compute)
    float4 aReg, bR00, bR01, bR10, bR11;
    {
        aReg = *(const float4*)(arow1 + kq);     // k0 = 0
        const float* w0 = W1 + (size_t)kb * MIDD + n0;
        const float* w1 = W1 + (size_t)(kb + 16) * MIDD + n0;
        bR00 = *(const float4*)(w0 + ng * 4);
        bR01 = *(const float4*)(w0 + ng * 4 + 64);
        bR10 = *(const float4*)(w1 + ng * 4);
        bR11 = *(const float4*)(w1 + ng * 4 + 64);
    }

    for (int kt = 0; kt < KTOT / 32; ++kt) {
        // write previously-fetched tile to LDS
        As[kq + 0][m_st] = aReg.x;
        As[kq + 1][m_st] = aReg.y;
        As[kq + 2][m_st] = aReg.z;
        As[kq + 3][m_st] = aReg.w;
        *(float4*)&Bs[kb][ng * 4]           = bR00;
        *(float4*)&Bs[kb][ng * 4 + 64]      = bR01;
        *(float4*)&Bs[kb + 16][ng * 4]      = bR10;
        *(float4*)&Bs[kb + 16][ng * 4 + 64] = bR11;
        __syncthreads();

        // issue next tile's global loads (latency overlaps the 32 k-steps)
        if (kt + 1 < KTOT / 32) {
            const int k0 = (kt + 1) * 32;        // multiple of 32 -> never straddles HH
            const float* s = (k0 < HH) ? (arow1 + k0) : (arow2 + (k0 - HH));
            aReg = *(const float4*)(s + kq);
            const float* w0 = W1 + (size_t)(k0 + kb) * MIDD + n0;
            const float* w1 = W1 + (size_t)(k0 + kb + 16) * MIDD + n0;
            bR00 = *(const float4*)(w0 + ng * 4);
            bR01 = *(const float4*)(w0 + ng * 4 + 64);
            bR10 = *(const float4*)(w1 + ng * 4);
            bR11 = *(const float4*)(w1 + ng * 4 + 64);
        }

        #pragma unroll
        for (int k = 0; k < 32; ++k) {
            const float4 av = *(const float4*)&As[k][rg * 4];   // 2 addr/wave: broadcast
            const float4 bv = *(const float4*)&Bs[k][cg * 4];   // 2-way: free
            const float ar[4] = {av.x, av.y, av.z, av.w};
            #pragma unroll
            for (int r = 0; r < 4; ++r) {
                acc[r][0] += ar[r] * bv.x;
                acc[r][1] += ar[r] * bv.y;
                acc[r][2] += ar[r] * bv.z;
                acc[r][3] += ar[r] * bv.w;
            }
        }
        __syncthreads();
    }

    // epilogue: bias + relu + store
    const float4 b1v = *(const float4*)(b1 + n0 + cg * 4);
    #pragma unroll
    for (int r = 0; r < 4; ++r) {
        const int i = i0 + rg * 4 + r;
        if (i < MAXN) {
            float4 o;
            o.x = fmaxf(acc[r][0] + b1v.x, 0.f);
            o.y = fmaxf(acc[r][1] + b1v.y, 0.f);
            o.z = fmaxf(acc[r][2] + b1v.z, 0.f);
            o.w = fmaxf(acc[r][3] + b1v.w, 0.f);
            *(float4*)&h[((size_t)b * MAXN + i) * MIDD + n0 + cg * 4] = o;
        }
    }
}

// ---------------------------------------------------------------------------
// K2: fused GEMM2 + bias + log-softmax + NLL + argmax.
// Block = 16 rows (4 waves x 4 rows). Lane l owns logit cols l and l+64.
// K-tiled over 768 in chunks of 64 (h tile + W2 tile in LDS).
// Writes pred/label (as float) and per-block partial NLL sum (deterministic).
// ---------------------------------------------------------------------------
__global__ __launch_bounds__(256, 4)
void k2_head(const float* __restrict__ h, const int* __restrict__ rels,
             const int* __restrict__ rels_pos,
             const float* __restrict__ W2, const float* __restrict__ b2,
             float* __restrict__ out, float* __restrict__ partials)
{
    const int b   = blockIdx.y;
    const int i0  = blockIdx.x * 16;
    const int num = rels_pos[2 * b + 1];
    const int tid = threadIdx.x;
    const int blk = blockIdx.y * gridDim.x + blockIdx.x;

    // masked rows: pred = -1, label = -1
    if (tid < 16) {
        const int i = i0 + tid;
        if (i < MAXN && i >= num) {
            out[1 + b * MAXN + i] = -1.0f;
            out[1 + BB * MAXN + b * MAXN + i] = -1.0f;
        }
    }
    if (i0 >= num) { if (tid == 0) partials[blk] = 0.f; return; }

    __shared__ __align__(16) float hs[16][68];       // pad 64->68, keeps 16B align
    __shared__ __align__(16) float w2s[64 * LBL];    // linear copy, conflict-free reads
    __shared__ float wave_nll[4];

    const int lane = tid & 63;
    const int wv   = tid >> 6;
    const int c    = lane;
    const bool has2 = (lane + 64) < LBL;             // lanes 0..32
    const int c2   = has2 ? (lane + 64) : (LBL - 1);

    float acc0[4], acc1[4];
    const float bc  = b2[c];
    const float bc2 = b2[c2];
    #pragma unroll
    for (int r = 0; r < 4; ++r) { acc0[r] = bc; acc1[r] = bc2; }

    const int sr = tid >> 4;                 // 0..15 staging row
    const int sk = (tid & 15) * 4;           // k offset (4 floats/thread)
    const int hrow_i = min(i0 + sr, MAXN - 1);
    const float* hrow = h + ((size_t)b * MAXN + hrow_i) * MIDD;

    for (int kt = 0; kt < MIDD / 64; ++kt) {
        const int k0 = kt * 64;
        *(float4*)&hs[sr][sk] = *(const float4*)(hrow + k0 + sk);
        const float4* wsrc = (const float4*)(W2 + (size_t)k0 * LBL);  // 64*97 floats, 16B aligned
        #pragma unroll
        for (int j = 0; j < 7; ++j) {
            const int idx = tid + j * 256;
            if (idx < (64 * LBL) / 4) ((float4*)w2s)[idx] = wsrc[idx];
        }
        __syncthreads();

        #pragma unroll 2
        for (int kk = 0; kk < 64; kk += 4) {
            const float w10 = w2s[(kk + 0) * LBL + c];
            const float w11 = w2s[(kk + 1) * LBL + c];
            const float w12 = w2s[(kk + 2) * LBL + c];
            const float w13 = w2s[(kk + 3) * LBL + c];
            const float w20 = w2s[(kk + 0) * LBL + c2];
            const float w21 = w2s[(kk + 1) * LBL + c2];
            const float w22 = w2s[(kk + 2) * LBL + c2];
            const float w23 = w2s[(kk + 3) * LBL + c2];
            #pragma unroll
            for (int r = 0; r < 4; ++r) {
                const float4 a = *(const float4*)&hs[wv * 4 + r][kk];  // broadcast
                acc0[r] += a.x * w10 + a.y * w11 + a.z * w12 + a.w * w13;
                acc1[r] += a.x * w20 + a.y * w21 + a.z * w22 + a.w * w23;
            }
        }
        __syncthreads();
    }

    // per-row softmax / nll / argmax via wave reductions
    float nll_acc = 0.f;
    #pragma unroll
    for (int r = 0; r < 4; ++r) {
        const int i = i0 + wv * 4 + r;
        if (i >= num || i >= MAXN) continue;
        const float v1 = acc0[r];
        const float v2 = has2 ? acc1[r] : -INFINITY;
        float bv = v1; int bi = c;
        if (v2 > v1) { bv = v2; bi = lane + 64; }
        #pragma unroll
        for (int off = 32; off > 0; off >>= 1) {
            const float ov = __shfl_xor(bv, off);
            const int   oi = __shfl_xor(bi, off);
            if (ov > bv || (ov == bv && oi < bi)) { bv = ov; bi = oi; }  // first-max
        }
        float se = expf(v1 - bv) + (has2 ? expf(v2 - bv) : 0.f);
        #pragma unroll
        for (int off = 32; off > 0; off >>= 1) se += __shfl_xor(se, off);
        const int lbl = rels[b * MAXN + i];
        float tv = (c == lbl ? v1 : 0.f) + ((has2 && (lane + 64) == lbl) ? v2 : 0.f);
        #pragma unroll
        for (int off = 32; off > 0; off >>= 1) tv += __shfl_xor(tv, off);
        const float nll = bv + logf(se) - tv;     // m + lse - logit[label]
        if (lane == 0) {
            nll_acc += nll;
            out[1 + b * MAXN + i] = (float)bi;
            out[1 + BB * MAXN + b * MAXN + i] = (float)lbl;
        }
    }
    if (lane == 0) wave_nll[wv] = nll_acc;
    __syncthreads();
    if (tid == 0)
        partials[blk] = wave_nll[0] + wave_nll[1] + wave_nll[2] + wave_nll[3];
}

// ---------------------------------------------------------------------------
// K3: reduce partial NLL sums, divide by mask count, write loss.
// ---------------------------------------------------------------------------
__global__ void k3_final(const float* __restrict__ partials,
                         const int* __restrict__ rels_pos, float* __restrict__ out)
{
    const int lane = threadIdx.x;   // 64 threads
    float v = 0.f;
    for (int idx = lane; idx < 26 * BB; idx += 64) v += partials[idx];
    #pragma unroll
    for (int off = 32; off > 0; off >>= 1) v += __shfl_xor(v, off);
    float cnt = (lane < BB) ? (float)min(max(rels_pos[2 * lane + 1], 0), MAXN) : 0.f;
    #pragma unroll
    for (int off = 32; off > 0; off >>= 1) cnt += __shfl_xor(cnt, off);
    if (lane == 0) out[0] = v / cnt;
}

extern "C" void kernel_launch(void* const* d_in, const int* in_sizes, int n_in,
                              void* d_out, int out_size, void* d_ws, size_t ws_size,
                              hipStream_t stream)
{
    const float* outs     = (const float*)d_in[0];
    const int*   rels     = (const int*)  d_in[1];
    const int*   rels_pos = (const int*)  d_in[2];
    const float* W1       = (const float*)d_in[3];
    const float* b1       = (const float*)d_in[4];
    const float* W2       = (const float*)d_in[5];
    const float* b2       = (const float*)d_in[6];
    float* out = (float*)d_out;

    float* h        = (float*)d_ws;                       // 6400 x 768 f32
    float* partials = h + (size_t)BB * MAXN * MIDD;       // 26*16 floats

    dim3 g1(MIDD / 128, (MAXN + 31) / 32, BB);            // (6, 13, 16)
    hipLaunchKernelGGL(k1_gemm1, g1, dim3(256), 0, stream, outs, rels_pos, W1, b1, h);

    dim3 g2((MAXN + 15) / 16, BB);                        // (26, 16)
    hipLaunchKernelGGL(k2_head, g2, dim3(256), 0, stream, h, rels, rels_pos, W2, b2, out, partials);

    hipLaunchKernelGGL(k3_final, dim3(1), dim3(64), 0, stream, partials, rels_pos, out);
}